// Round 5
// baseline (365.021 us; speedup 1.0000x reference)
//
#include <hip/hip_runtime.h>

typedef unsigned short u16;
typedef unsigned int u32;
typedef __attribute__((ext_vector_type(8))) short short8;
typedef __attribute__((ext_vector_type(4))) float f32x4;
typedef __attribute__((ext_vector_type(2))) float f32x2;

__device__ __forceinline__ float bf2f(u16 u) {
    return __uint_as_float(((u32)u) << 16);
}
__device__ __forceinline__ u16 f2bf(float f) {
    u32 u = __float_as_uint(f);
    u += 0x7fff + ((u >> 16) & 1);   // round-to-nearest-even
    return (u16)(u >> 16);
}
__device__ __forceinline__ u32 pack2(float a, float b) {
    return (u32)f2bf(a) | ((u32)f2bf(b) << 16);
}
// pack 4 floats -> 4 fp8 e4m3 in one u32
__device__ __forceinline__ u32 pk_fp8x4(float f0, float f1, float f2, float f3) {
    int w = __builtin_amdgcn_cvt_pk_fp8_f32(f0, f1, 0, false);
    w = __builtin_amdgcn_cvt_pk_fp8_f32(f2, f3, w, true);
    return (u32)w;
}
// accumulate 4 fp8 (one u32) into a[0..3]
__device__ __forceinline__ void acc4(float* a, u32 w) {
    f32x2 lo = __builtin_amdgcn_cvt_pk_f32_fp8((int)w, false);
    f32x2 hi = __builtin_amdgcn_cvt_pk_f32_fp8((int)w, true);
    a[0] += lo.x; a[1] += lo.y; a[2] += hi.x; a[3] += hi.y;
}
__device__ __forceinline__ void acc4m(float* a, u32 w, float m) {
    f32x2 lo = __builtin_amdgcn_cvt_pk_f32_fp8((int)w, false);
    f32x2 hi = __builtin_amdgcn_cvt_pk_f32_fp8((int)w, true);
    a[0] += m * lo.x; a[1] += m * lo.y; a[2] += m * hi.x; a[3] += m * hi.y;
}
__device__ __forceinline__ void acc16(float* a, uint4 v) {
    acc4(a + 0, v.x); acc4(a + 4, v.y); acc4(a + 8, v.z); acc4(a + 12, v.w);
}
__device__ __forceinline__ void acc16m(float* a, uint4 v, float m) {
    acc4m(a + 0, v.x, m); acc4m(a + 4, v.y, m); acc4m(a + 8, v.z, m); acc4m(a + 12, v.w, m);
}

// ---------------- conversions ----------------

// x fp32 -> xb bf16 [NPAD][256]  and  xq fp8 [NPAD][256]
__global__ void cvt_x_kernel(const float* __restrict__ x, u16* __restrict__ xb,
                             u32* __restrict__ xq, int n) {
    int i = blockIdx.x * 256 + threadIdx.x;   // group of 4 elements
    int row = i >> 6;                         // 64 groups per 256-wide row
    ushort4 o;
    u32 q;
    if (row < n) {
        float4 v = ((const float4*)x)[i];
        o.x = f2bf(v.x); o.y = f2bf(v.y); o.z = f2bf(v.z); o.w = f2bf(v.w);
        q = pk_fp8x4(v.x, v.y, v.z, v.w);
    } else {
        o.x = o.y = o.z = o.w = 0;
        q = 0;
    }
    ((ushort4*)xb)[i] = o;
    xq[i] = q;
}

// h bf16 -> fp8 copy (8 feats per thread)
__global__ void cvt_h_kernel(const u16* __restrict__ hb, uint2* __restrict__ hq, int ngroups) {
    int j = blockIdx.x * 256 + threadIdx.x;
    if (j >= ngroups) return;
    uint4 v = ((const uint4*)hb)[j];
    float f0 = bf2f(v.x & 0xffff), f1 = bf2f(v.x >> 16);
    float f2 = bf2f(v.y & 0xffff), f3 = bf2f(v.y >> 16);
    float f4 = bf2f(v.z & 0xffff), f5 = bf2f(v.z >> 16);
    float f6 = bf2f(v.w & 0xffff), f7 = bf2f(v.w >> 16);
    uint2 o;
    o.x = pk_fp8x4(f0, f1, f2, f3);
    o.y = pk_fp8x4(f4, f5, f6, f7);
    hq[j] = o;
}

// wT layout: [layer][n=256][k=512], k-contiguous (transposed weights, A rows then B rows)
__global__ void cvt_w_kernel(const float* __restrict__ WA, const float* __restrict__ WB,
                             const float* __restrict__ As, const float* __restrict__ Bs,
                             u16* __restrict__ wT, int nlayers) {
    int i = blockIdx.x * 256 + threadIdx.x;
    const int per = 256 * 512;
    if (i >= nlayers * per) return;
    int l = i / per;
    int rem = i - l * per;
    int nn = rem >> 9;
    int k = rem & 511;
    const float* Aw = (l == 0) ? WA : As + (size_t)(l - 1) * 65536;
    const float* Bw = (l == 0) ? WB : Bs + (size_t)(l - 1) * 65536;
    float v = (k < 256) ? Aw[(size_t)k * 256 + nn] : Bw[(size_t)(k - 256) * 256 + nn];
    wT[i] = f2bf(v);
}

// ---------------- CSR build: two-level counting sort ----------------
// Requires N <= 65536 so an edge packs into u32 as (dst<<16)|src.
// Coarse bucket b covers nodes [b*256, b*256+256).

// per-block LDS histogram of coarse buckets -> global ccnt[NB]
__global__ __launch_bounds__(256) void hist_kernel(const int* __restrict__ dst,
                                                   int* __restrict__ ccnt, int e, int nb) {
    __shared__ int h[256];
    int tid = threadIdx.x;
    h[tid] = 0;
    __syncthreads();
    int e0 = blockIdx.x * 4096;
#pragma unroll
    for (int j = 0; j < 16; ++j) {
        int i = e0 + j * 256 + tid;
        if (i < e) atomicAdd(&h[dst[i] >> 8], 1);
    }
    __syncthreads();
    if (tid < nb) {
        int v = h[tid];
        if (v) atomicAdd(&ccnt[tid], v);
    }
}

// single-block scan of coarse counts -> cbase[NB+1]; also rowptr[n]=e
__global__ __launch_bounds__(256) void scan_coarse_kernel(const int* __restrict__ ccnt,
                                                          int* __restrict__ cbase,
                                                          int* __restrict__ rowptr,
                                                          int nb, int n, int e) {
    __shared__ int sh[256];
    int t = threadIdx.x;
    int v = (t < nb) ? ccnt[t] : 0;
    int x = v;
    sh[t] = x; __syncthreads();
    for (int o = 1; o < 256; o <<= 1) {
        int y = (t >= o) ? sh[t - o] : 0;
        __syncthreads();
        x += y; sh[t] = x; __syncthreads();
    }
    if (t < nb) cbase[t] = x - v;
    if (t == 0) { cbase[nb] = e; rowptr[n] = e; }
}

// scatter packed edges into coarse regions of tmp; per-block chunk reservation
__global__ __launch_bounds__(256) void passA_kernel(const int* __restrict__ src,
                                                    const int* __restrict__ dst,
                                                    const int* __restrict__ cbase,
                                                    int* __restrict__ cfill,
                                                    u32* __restrict__ tmp, int e, int nb) {
    __shared__ int ph[256], pb[256], pr[256], cb[256];
    __shared__ u32 ed[4096];
    int tid = threadIdx.x;
    ph[tid] = 0; pr[tid] = 0;
    cb[tid] = (tid < nb) ? cbase[tid] : 0;
    __syncthreads();
    int e0 = blockIdx.x * 4096;
#pragma unroll
    for (int j = 0; j < 16; ++j) {
        int i = e0 + j * 256 + tid;
        u32 p = 0xFFFFFFFFu;
        if (i < e) {
            int d = dst[i];
            p = ((u32)d << 16) | (u32)src[i];
            atomicAdd(&ph[d >> 8], 1);
        }
        ed[j * 256 + tid] = p;
    }
    __syncthreads();
    pb[tid] = (tid < nb && ph[tid]) ? atomicAdd(&cfill[tid], ph[tid]) : 0;
    __syncthreads();
#pragma unroll
    for (int j = 0; j < 16; ++j) {
        u32 p = ed[j * 256 + tid];
        if (p != 0xFFFFFFFFu) {
            int bk = p >> 24;
            int r = atomicAdd(&pr[bk], 1);
            tmp[cb[bk] + pb[bk] + r] = p;
        }
    }
}

// per coarse bucket: per-node hist + scan -> rowptr/invd, then LDS-ranked scatter -> srcs
__global__ __launch_bounds__(256) void passB_kernel(const u32* __restrict__ tmp,
                                                    const int* __restrict__ cbase,
                                                    int* __restrict__ rowptr,
                                                    float* __restrict__ invd,
                                                    int* __restrict__ srcs, int n) {
    __shared__ int h[256], loc[256], cnt2[256], sh[256];
    int b = blockIdx.x;
    int tid = threadIdx.x;
    int base = cbase[b];
    int cnt = cbase[b + 1] - base;
    int node0 = b << 8;
    h[tid] = 0; cnt2[tid] = 0;
    __syncthreads();
    for (int i = tid; i < cnt; i += 256)
        atomicAdd(&h[(tmp[base + i] >> 16) & 255], 1);
    __syncthreads();
    int c = h[tid];
    int x = c;
    sh[tid] = x; __syncthreads();
    for (int o = 1; o < 256; o <<= 1) {
        int y = (tid >= o) ? sh[tid - o] : 0;
        __syncthreads();
        x += y; sh[tid] = x; __syncthreads();
    }
    loc[tid] = x - c;   // exclusive offset within bucket
    int node = node0 + tid;
    if (node < n) {
        rowptr[node] = base + x - c;
        invd[node] = 1.0f / (float)(c > 0 ? c : 1);
    }
    __syncthreads();
    for (int i = tid; i < cnt; i += 256) {
        u32 p = tmp[base + i];
        int ln = (p >> 16) & 255;
        int r = atomicAdd(&cnt2[ln], 1);
        srcs[base + loc[ln] + r] = (int)(p & 0xffffu);
    }
}

// ---------------- mean aggregation: one wave per node, fp8 gather ----------------
// fp8 row = 256B; 16 lanes x 16B cover a row; 4 edges per wave-load, x2 unroll
// -> 8 edges in flight. Output mean row written as bf16 to mb.

__global__ __launch_bounds__(256) void agg_kernel(const unsigned char* __restrict__ q,
                                                  u16* __restrict__ mb,
                                                  const int* __restrict__ rowptr,
                                                  const int* __restrict__ srcs,
                                                  const float* __restrict__ invd,
                                                  int n, int npad) {
    int gw = (blockIdx.x * 256 + threadIdx.x) >> 6;  // node id
    int lane = threadIdx.x & 63;
    int qd = lane >> 4;          // edge slot within group of 4
    int fl = lane & 15;          // 16B chunk (16 feats) within the row
    if (gw >= npad) return;
    u16* orow = mb + (size_t)gw * 256;
    if (gw >= n) {
        if (lane < 16) {
            uint4 z; z.x = z.y = z.z = z.w = 0;
            uint4* p = (uint4*)(orow + lane * 16);
            p[0] = z; p[1] = z;
        }
        return;
    }
    int beg = rowptr[gw], end = rowptr[gw + 1];
    float a[16];
#pragma unroll
    for (int i = 0; i < 16; ++i) a[i] = 0.f;
    for (int base = beg; base < end; base += 64) {
        int cnt = end - base;
        if (cnt > 64) cnt = 64;
        int el = (lane < cnt) ? srcs[base + lane] : 0;
        int t = 0;
        for (; 4 * t + 8 <= cnt; t += 2) {
            int s0 = __shfl(el, 4 * t + qd);
            int s1 = __shfl(el, 4 * t + 4 + qd);
            uint4 v0 = *(const uint4*)(q + (size_t)s0 * 256 + fl * 16);
            uint4 v1 = *(const uint4*)(q + (size_t)s1 * 256 + fl * 16);
            acc16(a, v0);
            acc16(a, v1);
        }
        for (; 4 * t < cnt; ++t) {
            int ei = 4 * t + qd;
            int sj = __shfl(el, ei & 63);
            float m = (ei < cnt) ? 1.0f : 0.0f;
            uint4 v = *(const uint4*)(q + (size_t)sj * 256 + fl * 16);
            acc16m(a, v, m);
        }
    }
    // reduce the 4 quarters
#pragma unroll
    for (int i = 0; i < 16; ++i) {
        a[i] += __shfl_xor(a[i], 16);
        a[i] += __shfl_xor(a[i], 32);
    }
    if (lane < 16) {
        float sc = invd[gw];
        uint4 o0, o1;
        o0.x = pack2(a[0] * sc, a[1] * sc);
        o0.y = pack2(a[2] * sc, a[3] * sc);
        o0.z = pack2(a[4] * sc, a[5] * sc);
        o0.w = pack2(a[6] * sc, a[7] * sc);
        o1.x = pack2(a[8] * sc, a[9] * sc);
        o1.y = pack2(a[10] * sc, a[11] * sc);
        o1.z = pack2(a[12] * sc, a[13] * sc);
        o1.w = pack2(a[14] * sc, a[15] * sc);
        uint4* p = (uint4*)(orow + lane * 16);
        p[0] = o0; p[1] = o1;
    }
}

// ---------------- fused GEMM: out = act([m | cur] @ wT^T), 64x256 tile ----------------
// A: rows from m (k<256) then cur (k>=256), both [NPAD][256] bf16 row-major.
// B: wT layer slice [n=256][k=512] bf16, k-contiguous. One block covers all 256 cols.
// Double-buffered LDS, one barrier per k-step; XOR-swizzled segment placement
// (phys slot p holds logical seg (p-row)&3) -> conflict-free ds_read_b128.
// fin=1: instead of storing h, dot rows against wo (fp32 [256]) + bias -> out[row].

__global__ __launch_bounds__(256) void gemm_kernel(const u16* __restrict__ mA,
                                                   const u16* __restrict__ cur,
                                                   const u16* __restrict__ wT,
                                                   u16* __restrict__ outb,
                                                   const float* __restrict__ wo,
                                                   const float* __restrict__ bo,
                                                   float* __restrict__ out,
                                                   int n, int apply_sigmoid, int fin) {
    __shared__ u16 lA[2][64 * 32];
    __shared__ u16 lB[2][256 * 32];
    __shared__ float lO[4][64];
    int r0 = blockIdx.x * 64;
    int tid = threadIdx.x;
    int lane = tid & 63;
    int w = tid >> 6;                  // wave -> col group w*64
    int lrow = lane & 15, quad = lane >> 4;

    f32x4 acc[4][4] = {};

    auto stage = [&](int ks, int b) {
        int k0 = ks * 32;
        const u16* sA = (k0 < 256) ? mA : cur;
        int kk = k0 & 255;
        {
            int li = tid;              // 256 A slots: 64 rows x 4 segs
            int row = li >> 2;
            int ls = ((li & 3) - row) & 3;     // logical seg placed at this phys slot
            const u16* g = sA + (size_t)(r0 + row) * 256 + kk + ls * 8;
            __builtin_amdgcn_global_load_lds(
                (const __attribute__((address_space(1))) u32*)g,
                (__attribute__((address_space(3))) u32*)(&lA[b][(size_t)li * 8]), 16, 0, 0);
        }
#pragma unroll
        for (int p = 0; p < 4; ++p) {
            int li = p * 256 + tid;    // 1024 B slots: 256 rows x 4 segs
            int row = li >> 2;
            int ls = ((li & 3) - row) & 3;
            const u16* g = wT + (size_t)row * 512 + k0 + ls * 8;
            __builtin_amdgcn_global_load_lds(
                (const __attribute__((address_space(1))) u32*)g,
                (__attribute__((address_space(3))) u32*)(&lB[b][(size_t)li * 8]), 16, 0, 0);
        }
    };

    stage(0, 0);
    int buf = 0;
    for (int ks = 0; ks < 16; ++ks) {
        __syncthreads();               // drains prefetch issued last iter (overlapped w/ MFMA)
        if (ks < 15) stage(ks + 1, buf ^ 1);
        short8 a[4], b4[4];
#pragma unroll
        for (int rt = 0; rt < 4; ++rt) {
            int row = rt * 16 + lrow;
            int ps = (quad + row) & 3;
            a[rt] = *(const short8*)(&lA[buf][(size_t)row * 32 + ps * 8]);
        }
#pragma unroll
        for (int ct = 0; ct < 4; ++ct) {
            int row = w * 64 + ct * 16 + lrow;
            int ps = (quad + row) & 3;
            b4[ct] = *(const short8*)(&lB[buf][(size_t)row * 32 + ps * 8]);
        }
#pragma unroll
        for (int rt = 0; rt < 4; ++rt)
#pragma unroll
            for (int ct = 0; ct < 4; ++ct)
                acc[rt][ct] = __builtin_amdgcn_mfma_f32_16x16x32_bf16(a[rt], b4[ct], acc[rt][ct], 0, 0, 0);
        buf ^= 1;
    }

    if (!fin) {
#pragma unroll
        for (int rt = 0; rt < 4; ++rt) {
            int rbase = r0 + rt * 16 + quad * 4;
#pragma unroll
            for (int r = 0; r < 4; ++r) {
                int row = rbase + r;
                if (row < n) {
#pragma unroll
                    for (int ct = 0; ct < 4; ++ct) {
                        float v = acc[rt][ct][r];
                        if (apply_sigmoid) v = 1.0f / (1.0f + __expf(-v));
                        outb[(size_t)row * 256 + w * 64 + ct * 16 + lrow] = f2bf(v);
                    }
                }
            }
        }
    } else {
        // final layer: sigmoid then dot with wo, reduce, write out
        float wv[4];
#pragma unroll
        for (int ct = 0; ct < 4; ++ct) wv[ct] = wo[w * 64 + ct * 16 + lrow];
#pragma unroll
        for (int rt = 0; rt < 4; ++rt) {
#pragma unroll
            for (int r = 0; r < 4; ++r) {
                float s = 0.f;
#pragma unroll
                for (int ct = 0; ct < 4; ++ct) {
                    float v = acc[rt][ct][r];
                    v = 1.0f / (1.0f + __expf(-v));
                    s += v * wv[ct];
                }
                s += __shfl_xor(s, 1);
                s += __shfl_xor(s, 2);
                s += __shfl_xor(s, 4);
                s += __shfl_xor(s, 8);
                if (lrow == 0) lO[w][rt * 16 + quad * 4 + r] = s;
            }
        }
        __syncthreads();
        if (tid < 64) {
            int row = r0 + tid;
            if (row < n) out[row] = lO[0][tid] + lO[1][tid] + lO[2][tid] + lO[3][tid] + bo[0];
        }
    }
}

// ---------------- launch ----------------

extern "C" void kernel_launch(void* const* d_in, const int* in_sizes, int n_in,
                              void* d_out, int out_size, void* d_ws, size_t ws_size,
                              hipStream_t stream) {
    const float* x  = (const float*)d_in[0];
    const int*   ei = (const int*)d_in[1];
    const float* WA = (const float*)d_in[2];
    const float* WB = (const float*)d_in[3];
    const float* As = (const float*)d_in[4];
    const float* Bs = (const float*)d_in[5];
    const float* Wo = (const float*)d_in[6];
    const float* bo = (const float*)d_in[7];
    float* out = (float*)d_out;

    const int H = 256;
    int N = in_sizes[0] / H;
    int E = in_sizes[1] / 2;
    int L = in_sizes[4] / (H * H);
    int NPAD = (N + 127) & ~127;
    int NB = (N + 255) >> 8;           // coarse buckets (requires N <= 65536)

    char* wsp = (char*)d_ws;
    size_t off = 0;
    auto alloc = [&](size_t b) { size_t o = off; off += (b + 255) & ~(size_t)255; return o; };
    int*   rowptr = (int*)(wsp + alloc((size_t)(NPAD + 1) * 4));
    int*   ccnt   = (int*)(wsp + alloc(1024));
    int*   cbase  = (int*)(wsp + alloc(1032 + 256));
    int*   cfill  = (int*)(wsp + alloc(1024));
    float* invd   = (float*)(wsp + alloc((size_t)NPAD * 4));
    int*   srcs   = (int*)(wsp + alloc((size_t)E * 4));
    u16*   xb     = (u16*)(wsp + alloc((size_t)NPAD * H * 2));
    u16*   hbuf   = (u16*)(wsp + alloc((size_t)NPAD * H * 2));
    u16*   mb     = (u16*)(wsp + alloc((size_t)NPAD * H * 2));
    u32*   xq     = (u32*)(wsp + alloc((size_t)NPAD * H));      // fp8 x
    uint2* hq     = (uint2*)(wsp + alloc((size_t)NPAD * H));    // fp8 h
    u16*   wT     = (u16*)(wsp + alloc((size_t)(L + 1) * 512 * 256 * 2));
    // tmp (packed coarse-sorted edges) aliases mb: dead until first agg writes mb
    u32*   tmp    = (u32*)mb;

    const int* esrc = ei;
    const int* edst = ei + E;

    hipMemsetAsync(ccnt, 0, 1024, stream);
    hipMemsetAsync(cfill, 0, 1024, stream);

    int gridE = (E + 4095) / 4096;
    cvt_x_kernel<<<NPAD / 4, 256, 0, stream>>>(x, xb, xq, N);
    cvt_w_kernel<<<((L + 1) * 512 * 256 + 255) / 256, 256, 0, stream>>>(WA, WB, As, Bs, wT, L + 1);
    hist_kernel<<<gridE, 256, 0, stream>>>(edst, ccnt, E, NB);
    scan_coarse_kernel<<<1, 256, 0, stream>>>(ccnt, cbase, rowptr, NB, N, E);
    passA_kernel<<<gridE, 256, 0, stream>>>(esrc, edst, cbase, cfill, tmp, E, NB);
    passB_kernel<<<NB, 256, 0, stream>>>(tmp, cbase, rowptr, invd, srcs, N);

    const u16* cur = xb;
    const unsigned char* curq = (const unsigned char*)xq;
    for (int s = 0; s <= L; ++s) {
        int fin = (s == L) ? 1 : 0;
        agg_kernel<<<NPAD / 4, 256, 0, stream>>>(curq, mb, rowptr, srcs, invd, N, NPAD);
        // in-place h update is safe: each gemm block reads exactly the rows it writes,
        // and all its reads (K-loop) precede its writes (epilogue).
        gemm_kernel<<<NPAD / 64, 256, 0, stream>>>(mb, cur, wT + (size_t)s * 512 * 256, hbuf,
                                                   Wo, bo, out, N, s > 0 ? 1 : 0, fin);
        if (!fin) {
            cvt_h_kernel<<<(N * 32 + 255) / 256, 256, 0, stream>>>(hbuf, hq, N * 32);
            cur = hbuf;
            curq = (const unsigned char*)hq;
        }
    }
}